// Round 2
// baseline (341.287 us; speedup 1.0000x reference)
//
#include <hip/hip_runtime.h>

#define Hdim 128
#define Wdim 128
#define Cdim 64
#define Bdim 4
#define HW   (Hdim * Wdim)
#define NPIX (Bdim * Hdim * Wdim)   // 65536

// ---------------------------------------------------------------------------
// Kernel 1: offset = pointwise(p_pw) . depthwise3x3(p_dw) applied to x
// Block = 256 thr = 4 waves; wave g owns channels [g*16, g*16+16) for 64
// consecutive pixels (lane = pixel). Partial acc[18] reduced through LDS.
// ---------------------------------------------------------------------------
__global__ __launch_bounds__(256, 4) void offset_kernel(
    const float* __restrict__ x,     // (B, C, H, W)
    const float* __restrict__ p_dw,  // (C, 1, 3, 3)
    const float* __restrict__ p_pw,  // (18, C, 1, 1)
    float* __restrict__ off)         // (NPIX, 18)  pixel-major
{
    __shared__ float part[4][64][18];   // 18.4 KB

    int lane = threadIdx.x & 63;
    int g    = threadIdx.x >> 6;        // wave id = channel group
    int pix0 = blockIdx.x * 64;
    int pix  = pix0 + lane;
    int w = pix & (Wdim - 1);
    int h = (pix >> 7) & (Hdim - 1);
    int b = pix >> 14;

    float acc[18];
#pragma unroll
    for (int j = 0; j < 18; ++j) acc[j] = 0.f;

#pragma unroll 4
    for (int i = 0; i < 16; ++i) {
        int c = g * 16 + i;             // wave-uniform
        const float* xb = x + (size_t)(b * Cdim + c) * HW;
        float t = 0.f;
#pragma unroll
        for (int dh = -1; dh <= 1; ++dh) {
            int hh = h + dh;
            bool okh = (hh >= 0) & (hh < Hdim);
#pragma unroll
            for (int dw = -1; dw <= 1; ++dw) {
                int ww = w + dw;
                bool ok = okh & (ww >= 0) & (ww < Wdim);
                float v = ok ? xb[hh * Wdim + ww] : 0.f;
                t += v * p_dw[c * 9 + (dh + 1) * 3 + (dw + 1)];
            }
        }
#pragma unroll
        for (int j = 0; j < 18; ++j)
            acc[j] += p_pw[j * Cdim + c] * t;   // wave-uniform weight -> s_load
    }

#pragma unroll
    for (int j = 0; j < 18; ++j) part[g][lane][j] = acc[j];
    __syncthreads();

    // reduce 4 partials, write 64*18 contiguous floats
    for (int idx = threadIdx.x; idx < 64 * 18; idx += 256) {
        int p = idx / 18;
        int j = idx - p * 18;
        float s = part[0][p][j] + part[1][p][j] + part[2][p][j] + part[3][p][j];
        off[(size_t)(pix0 + p) * 18 + j] = s;
    }
}

// ---------------------------------------------------------------------------
// Kernel 2: deformable bilinear sampling + collapsed stride-3 depthwise (c_dw)
// + pointwise (c_pw).  Phase A: wave g computes acc for channels g*16..+16 of
// 64 consecutive pixels (coalesced gathers) -> LDS [c][pixel].
// Phase B: wave g computes output channels g*16..+16 (wave-uniform weights).
// ---------------------------------------------------------------------------
__global__ __launch_bounds__(256, 4) void deform_kernel(
    const float* __restrict__ x,     // (B, C, H, W)
    const float* __restrict__ c_dw,  // (C, 1, 3, 3)
    const float* __restrict__ c_pw,  // (C, C, 1, 1)
    const float* __restrict__ off,   // (NPIX, 18)
    float* __restrict__ out)         // (B, C, H, W)
{
    __shared__ float accs[Cdim][64];    // [channel][pixel] 16 KB

    int lane = threadIdx.x & 63;
    int g    = threadIdx.x >> 6;
    int pix0 = blockIdx.x * 64;
    int pix  = pix0 + lane;
    int w = pix & (Wdim - 1);
    int h = (pix >> 7) & (Hdim - 1);
    int b = pix >> 14;

    const float* o     = off + (size_t)pix * 18;
    const float* xbase = x + (size_t)b * Cdim * HW;

    float acc[16];
#pragma unroll
    for (int i = 0; i < 16; ++i) acc[i] = 0.f;

    for (int k = 0; k < 9; ++k) {
        // p = p0 + p_n + offset   (padded coords, Hp=Wp=130)
        float px = (float)(h + 1) + (float)(k / 3 - 1) + o[k];
        float py = (float)(w + 1) + (float)(k % 3 - 1) + o[k + 9];

        float fx = floorf(px), fy = floorf(py);
        float ltx = fminf(fmaxf(fx, 0.f), 129.f);
        float lty = fminf(fmaxf(fy, 0.f), 129.f);
        float rbx = fminf(fmaxf(fx + 1.f, 0.f), 129.f);
        float rby = fminf(fmaxf(fy + 1.f, 0.f), 129.f);
        float pxc = fminf(fmaxf(px, 0.f), 129.f);
        float pyc = fminf(fmaxf(py, 0.f), 129.f);

        float glt = (1.f + ltx - pxc) * (1.f + lty - pyc);
        float grb = (1.f - rbx + pxc) * (1.f - rby + pyc);
        float glb = (1.f + ltx - pxc) * (1.f - rby + pyc);
        float grt = (1.f - rbx + pxc) * (1.f + lty - pyc);

        int ix0 = (int)ltx, iy0 = (int)lty, ix1 = (int)rbx, iy1 = (int)rby;
        // padded coord q maps to x coord q-1; nonzero only when 1<=q<=128
        float mx0 = (ix0 >= 1 && ix0 <= Hdim) ? 1.f : 0.f;
        float my0 = (iy0 >= 1 && iy0 <= Wdim) ? 1.f : 0.f;
        float mx1 = (ix1 >= 1 && ix1 <= Hdim) ? 1.f : 0.f;
        float my1 = (iy1 >= 1 && iy1 <= Wdim) ? 1.f : 0.f;
        glt *= mx0 * my0;
        grb *= mx1 * my1;
        glb *= mx0 * my1;
        grt *= mx1 * my0;
        int cx0 = min(max(ix0 - 1, 0), Hdim - 1);
        int cy0 = min(max(iy0 - 1, 0), Wdim - 1);
        int cx1 = min(max(ix1 - 1, 0), Hdim - 1);
        int cy1 = min(max(iy1 - 1, 0), Wdim - 1);
        int i00 = cx0 * Wdim + cy0;   // lt
        int i11 = cx1 * Wdim + cy1;   // rb
        int i01 = cx0 * Wdim + cy1;   // lb
        int i10 = cx1 * Wdim + cy0;   // rt

#pragma unroll
        for (int i = 0; i < 16; ++i) {
            const float* xb = xbase + (size_t)(g * 16 + i) * HW;
            float s = glt * xb[i00] + grb * xb[i11]
                    + glb * xb[i01] + grt * xb[i10];
            acc[i] += c_dw[(g * 16 + i) * 9 + k] * s;   // wave-uniform weight
        }
    }

#pragma unroll
    for (int i = 0; i < 16; ++i) accs[g * 16 + i][lane] = acc[i];
    __syncthreads();

    // Phase B: pointwise 64 -> 64.  oc wave-uniform -> scalar weight loads.
    float xv[Cdim];
#pragma unroll
    for (int c = 0; c < Cdim; ++c) xv[c] = accs[c][lane];

    int hw = pix & (HW - 1);
    size_t obase = (size_t)b * Cdim * HW + hw;
#pragma unroll 4
    for (int i = 0; i < 16; ++i) {
        int oc = g * 16 + i;
        float s = 0.f;
#pragma unroll
        for (int c = 0; c < Cdim; ++c)
            s += c_pw[oc * Cdim + c] * xv[c];
        out[obase + (size_t)oc * HW] = s;
    }
}

extern "C" void kernel_launch(void* const* d_in, const int* in_sizes, int n_in,
                              void* d_out, int out_size, void* d_ws, size_t ws_size,
                              hipStream_t stream) {
    const float* x    = (const float*)d_in[0];
    const float* p_dw = (const float*)d_in[1];
    const float* p_pw = (const float*)d_in[2];
    const float* c_dw = (const float*)d_in[3];
    const float* c_pw = (const float*)d_in[4];
    float* out = (float*)d_out;
    float* off = (float*)d_ws;   // NPIX * 18 floats = 4.72 MB

    dim3 blk(256);
    dim3 grd(NPIX / 64);   // 1024 blocks, 64 pixels each
    offset_kernel<<<grd, blk, 0, stream>>>(x, p_dw, p_pw, off);
    deform_kernel<<<grd, blk, 0, stream>>>(x, c_dw, c_pw, off, out);
}

// Round 3
// 151.579 us; speedup vs baseline: 2.2515x; 2.2515x over previous
//
#include <hip/hip_runtime.h>

#define Hdim 128
#define Wdim 128
#define Cdim 64
#define HW   (Hdim * Wdim)
#define NPIX (4 * HW)   // 65536

// ---------------------------------------------------------------------------
// Kernel 1: offset = pointwise(p_pw) . depthwise3x3(p_dw) applied to x
// Block = 256 thr = 4 waves; wave g owns channels [g*16, g*16+16) for 64
// consecutive pixels (lane = pixel). t[16] dw results -> 18 pointwise partials
// -> LDS reduce across the 4 waves. Output stored k-major (18, NPIX) so the
// deform kernel reads it coalesced.
// ---------------------------------------------------------------------------
__global__ __launch_bounds__(256) void offset_kernel(
    const float* __restrict__ x,     // (B, C, H, W)
    const float* __restrict__ p_dw,  // (C, 1, 3, 3)
    const float* __restrict__ p_pw,  // (18, C, 1, 1)
    float* __restrict__ off)         // (18, NPIX)  k-major
{
    __shared__ float part[4][18][64];   // 18.4 KB

    int lane = threadIdx.x & 63;
    int g    = threadIdx.x >> 6;
    int pix0 = blockIdx.x * 64;
    int pix  = pix0 + lane;
    int w = pix & (Wdim - 1);
    int h = (pix >> 7) & (Hdim - 1);
    int b = pix >> 14;

    // depthwise 3x3 for this wave's 16 channels at this pixel
    float t[16];
#pragma unroll
    for (int i = 0; i < 16; ++i) {
        int c = g * 16 + i;             // wave-uniform
        const float* xb = x + (size_t)(b * Cdim + c) * HW;
        float s = 0.f;
#pragma unroll
        for (int dh = -1; dh <= 1; ++dh) {
            int hh = h + dh;
            bool okh = (hh >= 0) & (hh < Hdim);
#pragma unroll
            for (int dw = -1; dw <= 1; ++dw) {
                int ww = w + dw;
                bool ok = okh & (ww >= 0) & (ww < Wdim);
                float v = ok ? xb[hh * Wdim + ww] : 0.f;
                s += v * p_dw[c * 9 + (dh + 1) * 3 + (dw + 1)];
            }
        }
        t[i] = s;
    }

    // pointwise partial: weights for row j are 16 contiguous floats -> s_load_dwordx4
#pragma unroll
    for (int j = 0; j < 18; ++j) {
        float s = 0.f;
#pragma unroll
        for (int i = 0; i < 16; ++i)
            s += p_pw[j * Cdim + g * 16 + i] * t[i];
        part[g][j][lane] = s;
    }
    __syncthreads();

    // reduce 4 partials; coalesced k-major writes
#pragma unroll
    for (int it = 0; it < 5; ++it) {
        int idx = threadIdx.x + it * 256;
        if (idx < 18 * 64) {
            int j = idx >> 6;
            int p = idx & 63;
            float s = part[0][j][p] + part[1][j][p] + part[2][j][p] + part[3][j][p];
            off[(size_t)j * NPIX + pix0 + p] = s;
        }
    }
}

// ---------------------------------------------------------------------------
// Kernel 2: deformable bilinear sampling + collapsed stride-3 depthwise (c_dw)
// + pointwise (c_pw).  Phase A: wave g computes acc for channels g*16..+16 of
// 64 consecutive pixels (coalesced gathers) -> LDS [c][pixel].
// Phase B: 64->64 pointwise read from LDS in 8-float chunks (no big per-thread
// array -> no spills; R2's xv[64] caused 880 MB of scratch traffic).
// ---------------------------------------------------------------------------
__global__ __launch_bounds__(256) void deform_kernel(
    const float* __restrict__ x,     // (B, C, H, W)
    const float* __restrict__ c_dw,  // (C, 1, 3, 3)
    const float* __restrict__ c_pw,  // (C, C, 1, 1)
    const float* __restrict__ off,   // (18, NPIX)
    float* __restrict__ out)         // (B, C, H, W)
{
    __shared__ float accs[Cdim][64];    // [channel][pixel] 16 KB

    int lane = threadIdx.x & 63;
    int g    = threadIdx.x >> 6;
    int pix0 = blockIdx.x * 64;
    int pix  = pix0 + lane;
    int w = pix & (Wdim - 1);
    int h = (pix >> 7) & (Hdim - 1);
    int b = pix >> 14;

    const float* xbase = x + (size_t)b * Cdim * HW + (size_t)g * 16 * HW;

    float acc[16];
#pragma unroll
    for (int i = 0; i < 16; ++i) acc[i] = 0.f;

    for (int k = 0; k < 9; ++k) {
        // p = p0 + p_n + offset   (padded coords, Hp=Wp=130)
        float px = (float)(h + 1) + (float)(k / 3 - 1) + off[(size_t)k * NPIX + pix];
        float py = (float)(w + 1) + (float)(k % 3 - 1) + off[(size_t)(k + 9) * NPIX + pix];

        float fx = floorf(px), fy = floorf(py);
        float ltx = fminf(fmaxf(fx, 0.f), 129.f);
        float lty = fminf(fmaxf(fy, 0.f), 129.f);
        float rbx = fminf(fmaxf(fx + 1.f, 0.f), 129.f);
        float rby = fminf(fmaxf(fy + 1.f, 0.f), 129.f);
        float pxc = fminf(fmaxf(px, 0.f), 129.f);
        float pyc = fminf(fmaxf(py, 0.f), 129.f);

        float glt = (1.f + ltx - pxc) * (1.f + lty - pyc);
        float grb = (1.f - rbx + pxc) * (1.f - rby + pyc);
        float glb = (1.f + ltx - pxc) * (1.f - rby + pyc);
        float grt = (1.f - rbx + pxc) * (1.f + lty - pyc);

        int ix0 = (int)ltx, iy0 = (int)lty, ix1 = (int)rbx, iy1 = (int)rby;
        // padded coord q maps to x coord q-1; nonzero only when 1<=q<=128
        float mx0 = (ix0 >= 1 && ix0 <= Hdim) ? 1.f : 0.f;
        float my0 = (iy0 >= 1 && iy0 <= Wdim) ? 1.f : 0.f;
        float mx1 = (ix1 >= 1 && ix1 <= Hdim) ? 1.f : 0.f;
        float my1 = (iy1 >= 1 && iy1 <= Wdim) ? 1.f : 0.f;
        glt *= mx0 * my0;
        grb *= mx1 * my1;
        glb *= mx0 * my1;
        grt *= mx1 * my0;
        int cx0 = min(max(ix0 - 1, 0), Hdim - 1);
        int cy0 = min(max(iy0 - 1, 0), Wdim - 1);
        int cx1 = min(max(ix1 - 1, 0), Hdim - 1);
        int cy1 = min(max(iy1 - 1, 0), Wdim - 1);
        int i00 = cx0 * Wdim + cy0;   // lt
        int i11 = cx1 * Wdim + cy1;   // rb
        int i01 = cx0 * Wdim + cy1;   // lb
        int i10 = cx1 * Wdim + cy0;   // rt

#pragma unroll
        for (int i = 0; i < 16; ++i) {
            const float* xb = xbase + (size_t)i * HW;
            float sv = glt * xb[i00] + grb * xb[i11]
                     + glb * xb[i01] + grt * xb[i10];
            acc[i] += c_dw[(g * 16 + i) * 9 + k] * sv;   // wave-uniform weight
        }
    }

#pragma unroll
    for (int i = 0; i < 16; ++i) accs[g * 16 + i][lane] = acc[i];
    __syncthreads();

    // Phase B: pointwise 64 -> 64 in 8-channel chunks; s[16]+xc[8] regs only.
    float s[16];
#pragma unroll
    for (int i = 0; i < 16; ++i) s[i] = 0.f;

    for (int c0 = 0; c0 < Cdim; c0 += 8) {
        float xc[8];
#pragma unroll
        for (int q = 0; q < 8; ++q) xc[q] = accs[c0 + q][lane];
#pragma unroll
        for (int i = 0; i < 16; ++i) {
#pragma unroll
            for (int q = 0; q < 8; ++q)
                s[i] += c_pw[(g * 16 + i) * Cdim + c0 + q] * xc[q];
        }
    }

    int hw = pix & (HW - 1);
    size_t obase = (size_t)b * Cdim * HW + hw;
#pragma unroll
    for (int i = 0; i < 16; ++i)
        out[obase + (size_t)(g * 16 + i) * HW] = s[i];
}

extern "C" void kernel_launch(void* const* d_in, const int* in_sizes, int n_in,
                              void* d_out, int out_size, void* d_ws, size_t ws_size,
                              hipStream_t stream) {
    const float* x    = (const float*)d_in[0];
    const float* p_dw = (const float*)d_in[1];
    const float* p_pw = (const float*)d_in[2];
    const float* c_dw = (const float*)d_in[3];
    const float* c_pw = (const float*)d_in[4];
    float* out = (float*)d_out;
    float* off = (float*)d_ws;   // 18 * NPIX floats = 4.72 MB

    dim3 blk(256);
    dim3 grd(NPIX / 64);   // 1024 blocks, 64 pixels each
    offset_kernel<<<grd, blk, 0, stream>>>(x, p_dw, p_pw, off);
    deform_kernel<<<grd, blk, 0, stream>>>(x, c_dw, c_pw, off, out);
}

// Round 4
// 141.413 us; speedup vs baseline: 2.4134x; 1.0719x over previous
//
#include <hip/hip_runtime.h>

#define Hdim 128
#define Wdim 128
#define Cdim 64
#define HW   (Hdim * Wdim)
#define NPIX (4 * HW)     // 65536
#define NBLK (NPIX / 64)  // 1024 blocks, 64 pixels each
#define NXCD 8

// XCD-aware bijective swizzle (nwg % 8 == 0): consecutive logical blocks
// (which share image rows -> x reuse) land on the SAME XCD's L2.
__device__ __forceinline__ int xcd_swizzle(int bid) {
    return (bid % NXCD) * (NBLK / NXCD) + bid / NXCD;
}

// ---------------------------------------------------------------------------
// Kernel 1: offset = pointwise(p_pw) . depthwise3x3(p_dw) applied to x
// 512 thr = 8 waves; wave g owns channels [g*8, g*8+8) for 64 consecutive
// pixels (lane = pixel). Partials reduced through LDS. Output k-major.
// ---------------------------------------------------------------------------
__global__ __launch_bounds__(512) void offset_kernel(
    const float* __restrict__ x,     // (B, C, H, W)
    const float* __restrict__ p_dw,  // (C, 1, 3, 3)
    const float* __restrict__ p_pw,  // (18, C, 1, 1)
    float* __restrict__ off)         // (18, NPIX)  k-major
{
    __shared__ float part[8][18][64];   // 36.8 KB

    int lane = threadIdx.x & 63;
    int g    = threadIdx.x >> 6;
    int blk  = xcd_swizzle(blockIdx.x);
    int pix0 = blk * 64;
    int pix  = pix0 + lane;
    int w = pix & (Wdim - 1);
    int h = (pix >> 7) & (Hdim - 1);
    int b = pix >> 14;

    // depthwise 3x3 for this wave's 8 channels at this pixel
    float t[8];
#pragma unroll
    for (int i = 0; i < 8; ++i) {
        int c = g * 8 + i;              // wave-uniform
        const float* xb = x + (size_t)(b * Cdim + c) * HW;
        float s = 0.f;
#pragma unroll
        for (int dh = -1; dh <= 1; ++dh) {
            int hh = h + dh;
            bool okh = (hh >= 0) & (hh < Hdim);
#pragma unroll
            for (int dw = -1; dw <= 1; ++dw) {
                int ww = w + dw;
                bool ok = okh & (ww >= 0) & (ww < Wdim);
                float v = ok ? xb[hh * Wdim + ww] : 0.f;
                s += v * p_dw[c * 9 + (dh + 1) * 3 + (dw + 1)];
            }
        }
        t[i] = s;
    }

    // pointwise partial: row j weights contiguous -> scalar loads
#pragma unroll
    for (int j = 0; j < 18; ++j) {
        float s = 0.f;
#pragma unroll
        for (int i = 0; i < 8; ++i)
            s += p_pw[j * Cdim + g * 8 + i] * t[i];
        part[g][j][lane] = s;
    }
    __syncthreads();

    // reduce 8 partials; coalesced k-major writes (18*64 = 1152 elements)
#pragma unroll
    for (int it = 0; it < 3; ++it) {
        int idx = threadIdx.x + it * 512;
        if (idx < 18 * 64) {
            int j = idx >> 6;
            int p = idx & 63;
            float s = 0.f;
#pragma unroll
            for (int q = 0; q < 8; ++q) s += part[q][j][p];
            off[(size_t)j * NPIX + pix0 + p] = s;
        }
    }
}

// ---------------------------------------------------------------------------
// Kernel 2: deformable bilinear sampling + collapsed stride-3 depthwise (c_dw)
// + pointwise (c_pw).  512 thr = 8 waves; wave g gathers channels g*8..+8
// (coalesced within wave: lane = consecutive pixel) -> LDS [c][pixel].
// Phase B: wave g computes output channels g*8..+8 (wave-uniform weights).
// ---------------------------------------------------------------------------
__global__ __launch_bounds__(512) void deform_kernel(
    const float* __restrict__ x,     // (B, C, H, W)
    const float* __restrict__ c_dw,  // (C, 1, 3, 3)
    const float* __restrict__ c_pw,  // (C, C, 1, 1)
    const float* __restrict__ off,   // (18, NPIX)
    float* __restrict__ out)         // (B, C, H, W)
{
    __shared__ float accs[Cdim][64];    // [channel][pixel] 16 KB

    int lane = threadIdx.x & 63;
    int g    = threadIdx.x >> 6;
    int blk  = xcd_swizzle(blockIdx.x);
    int pix0 = blk * 64;
    int pix  = pix0 + lane;
    int w = pix & (Wdim - 1);
    int h = (pix >> 7) & (Hdim - 1);
    int b = pix >> 14;

    const float* xbase = x + (size_t)b * Cdim * HW + (size_t)g * 8 * HW;

    float acc[8];
#pragma unroll
    for (int i = 0; i < 8; ++i) acc[i] = 0.f;

    for (int k = 0; k < 9; ++k) {
        // p = p0 + p_n + offset   (padded coords, Hp=Wp=130)
        float px = (float)(h + 1) + (float)(k / 3 - 1) + off[(size_t)k * NPIX + pix];
        float py = (float)(w + 1) + (float)(k % 3 - 1) + off[(size_t)(k + 9) * NPIX + pix];

        float fx = floorf(px), fy = floorf(py);
        float ltx = fminf(fmaxf(fx, 0.f), 129.f);
        float lty = fminf(fmaxf(fy, 0.f), 129.f);
        float rbx = fminf(fmaxf(fx + 1.f, 0.f), 129.f);
        float rby = fminf(fmaxf(fy + 1.f, 0.f), 129.f);
        float pxc = fminf(fmaxf(px, 0.f), 129.f);
        float pyc = fminf(fmaxf(py, 0.f), 129.f);

        float glt = (1.f + ltx - pxc) * (1.f + lty - pyc);
        float grb = (1.f - rbx + pxc) * (1.f - rby + pyc);
        float glb = (1.f + ltx - pxc) * (1.f - rby + pyc);
        float grt = (1.f - rbx + pxc) * (1.f + lty - pyc);

        int ix0 = (int)ltx, iy0 = (int)lty, ix1 = (int)rbx, iy1 = (int)rby;
        // padded coord q maps to x coord q-1; nonzero only when 1<=q<=128
        float mx0 = (ix0 >= 1 && ix0 <= Hdim) ? 1.f : 0.f;
        float my0 = (iy0 >= 1 && iy0 <= Wdim) ? 1.f : 0.f;
        float mx1 = (ix1 >= 1 && ix1 <= Hdim) ? 1.f : 0.f;
        float my1 = (iy1 >= 1 && iy1 <= Wdim) ? 1.f : 0.f;
        glt *= mx0 * my0;
        grb *= mx1 * my1;
        glb *= mx0 * my1;
        grt *= mx1 * my0;
        int cx0 = min(max(ix0 - 1, 0), Hdim - 1);
        int cy0 = min(max(iy0 - 1, 0), Wdim - 1);
        int cx1 = min(max(ix1 - 1, 0), Hdim - 1);
        int cy1 = min(max(iy1 - 1, 0), Wdim - 1);
        int i00 = cx0 * Wdim + cy0;   // lt
        int i11 = cx1 * Wdim + cy1;   // rb
        int i01 = cx0 * Wdim + cy1;   // lb
        int i10 = cx1 * Wdim + cy0;   // rt

#pragma unroll
        for (int i = 0; i < 8; ++i) {
            const float* xb = xbase + (size_t)i * HW;
            float sv = glt * xb[i00] + grb * xb[i11]
                     + glb * xb[i01] + grt * xb[i10];
            acc[i] += c_dw[(g * 8 + i) * 9 + k] * sv;   // wave-uniform weight
        }
    }

#pragma unroll
    for (int i = 0; i < 8; ++i) accs[g * 8 + i][lane] = acc[i];
    __syncthreads();

    // Phase B: pointwise 64 -> 64 in 8-channel chunks (no big arrays).
    float s[8];
#pragma unroll
    for (int i = 0; i < 8; ++i) s[i] = 0.f;

    for (int c0 = 0; c0 < Cdim; c0 += 8) {
        float xc[8];
#pragma unroll
        for (int q = 0; q < 8; ++q) xc[q] = accs[c0 + q][lane];
#pragma unroll
        for (int i = 0; i < 8; ++i) {
#pragma unroll
            for (int q = 0; q < 8; ++q)
                s[i] += c_pw[(g * 8 + i) * Cdim + c0 + q] * xc[q];
        }
    }

    int hw = pix & (HW - 1);
    size_t obase = (size_t)b * Cdim * HW + hw;
#pragma unroll
    for (int i = 0; i < 8; ++i)
        out[obase + (size_t)(g * 8 + i) * HW] = s[i];
}

extern "C" void kernel_launch(void* const* d_in, const int* in_sizes, int n_in,
                              void* d_out, int out_size, void* d_ws, size_t ws_size,
                              hipStream_t stream) {
    const float* x    = (const float*)d_in[0];
    const float* p_dw = (const float*)d_in[1];
    const float* p_pw = (const float*)d_in[2];
    const float* c_dw = (const float*)d_in[3];
    const float* c_pw = (const float*)d_in[4];
    float* out = (float*)d_out;
    float* off = (float*)d_ws;   // 18 * NPIX floats = 4.72 MB

    dim3 blk(512);
    dim3 grd(NBLK);   // 1024 blocks, 64 pixels each
    offset_kernel<<<grd, blk, 0, stream>>>(x, p_dw, p_pw, off);
    deform_kernel<<<grd, blk, 0, stream>>>(x, c_dw, c_pw, off, out);
}

// Round 5
// 127.526 us; speedup vs baseline: 2.6762x; 1.1089x over previous
//
#include <hip/hip_runtime.h>

#define Hdim 128
#define Wdim 128
#define Cdim 64
#define HW   (Hdim * Wdim)
#define NPIX (4 * HW)     // 65536
#define NBLK (NPIX / 64)  // 1024 blocks, 64 pixels each
#define NXCD 8

// XCD-aware bijective swizzle (nwg % 8 == 0): consecutive logical blocks
// (which share image rows -> x reuse) land on the SAME XCD's L2.
__device__ __forceinline__ int xcd_swizzle(int bid) {
    return (bid % NXCD) * (NBLK / NXCD) + bid / NXCD;
}

// ---------------------------------------------------------------------------
// Kernel 0: NCHW -> NHWC transpose of x (so deform gathers are coalesced:
// one pixel's 64 channels = 256 contiguous bytes).
// ---------------------------------------------------------------------------
__global__ __launch_bounds__(512) void transpose_kernel(
    const float* __restrict__ x,   // (B, C, H, W)
    float* __restrict__ xt)        // (B, H, W, C)
{
    __shared__ float tile[64][65];
    int lane = threadIdx.x & 63;
    int g    = threadIdx.x >> 6;
    int blk  = xcd_swizzle(blockIdx.x);
    int pix0 = blk * 64;
    int b    = pix0 >> 14;
    int hw0  = pix0 & (HW - 1);

#pragma unroll
    for (int i = 0; i < 8; ++i) {
        int c = g * 8 + i;
        tile[c][lane] = x[(size_t)(b * Cdim + c) * HW + hw0 + lane];
    }
    __syncthreads();
#pragma unroll
    for (int i = 0; i < 8; ++i) {
        int p = g * 8 + i;
        xt[(size_t)(pix0 + p) * Cdim + lane] = tile[lane][p];
    }
}

// ---------------------------------------------------------------------------
// Kernel 1: offset = pointwise(p_pw) . depthwise3x3(p_dw) applied to x
// (unchanged from R4 — stencil reads are coalesced in NCHW). Output k-major.
// ---------------------------------------------------------------------------
__global__ __launch_bounds__(512) void offset_kernel(
    const float* __restrict__ x,     // (B, C, H, W)
    const float* __restrict__ p_dw,  // (C, 1, 3, 3)
    const float* __restrict__ p_pw,  // (18, C, 1, 1)
    float* __restrict__ off)         // (18, NPIX)  k-major
{
    __shared__ float part[8][18][64];   // 36.8 KB

    int lane = threadIdx.x & 63;
    int g    = threadIdx.x >> 6;
    int blk  = xcd_swizzle(blockIdx.x);
    int pix0 = blk * 64;
    int pix  = pix0 + lane;
    int w = pix & (Wdim - 1);
    int h = (pix >> 7) & (Hdim - 1);
    int b = pix >> 14;

    float t[8];
#pragma unroll
    for (int i = 0; i < 8; ++i) {
        int c = g * 8 + i;
        const float* xb = x + (size_t)(b * Cdim + c) * HW;
        float s = 0.f;
#pragma unroll
        for (int dh = -1; dh <= 1; ++dh) {
            int hh = h + dh;
            bool okh = (hh >= 0) & (hh < Hdim);
#pragma unroll
            for (int dw = -1; dw <= 1; ++dw) {
                int ww = w + dw;
                bool ok = okh & (ww >= 0) & (ww < Wdim);
                float v = ok ? xb[hh * Wdim + ww] : 0.f;
                s += v * p_dw[c * 9 + (dh + 1) * 3 + (dw + 1)];
            }
        }
        t[i] = s;
    }

#pragma unroll
    for (int j = 0; j < 18; ++j) {
        float s = 0.f;
#pragma unroll
        for (int i = 0; i < 8; ++i)
            s += p_pw[j * Cdim + g * 8 + i] * t[i];
        part[g][j][lane] = s;
    }
    __syncthreads();

#pragma unroll
    for (int it = 0; it < 3; ++it) {
        int idx = threadIdx.x + it * 512;
        if (idx < 18 * 64) {
            int j = idx >> 6;
            int p = idx & 63;
            float s = 0.f;
#pragma unroll
            for (int q = 0; q < 8; ++q) s += part[q][j][p];
            off[(size_t)j * NPIX + pix0 + p] = s;
        }
    }
}

// ---------------------------------------------------------------------------
// Kernel 2: deformable sampling + collapsed depthwise + pointwise.
// Phase A: lane = CHANNEL. Wave g owns 8 pixels; per (pixel,k) the geometry
// is wave-uniform, so each bilinear corner is ONE coalesced 256B read of
// x_t[..][0..63] (4 cache lines vs ~64 with lane=pixel). Offset reads are
// wave-uniform -> scalar loads. acc -> LDS [pixel][channel].
// Phase B: lane = pixel; 64->64 pointwise, coalesced NCHW writes.
// ---------------------------------------------------------------------------
__global__ __launch_bounds__(512) void deform_kernel(
    const float* __restrict__ xt,    // (B, H, W, C)
    const float* __restrict__ c_dw,  // (C, 1, 3, 3)
    const float* __restrict__ c_pw,  // (C, C, 1, 1)
    const float* __restrict__ off,   // (18, NPIX)
    float* __restrict__ out)         // (B, C, H, W)
{
    __shared__ float accs[64][65];   // [pixel][channel] padded, 16.6 KB
    __shared__ float cdwT[9 * 64];   // c_dw transposed [k][c], 2.3 KB

    int lane = threadIdx.x & 63;
    int g    = threadIdx.x >> 6;
    int blk  = xcd_swizzle(blockIdx.x);
    int pix0 = blk * 64;

    // stage c_dw transposed: cdwT[k][c] = c_dw[c*9+k]
    for (int idx = threadIdx.x; idx < 9 * 64; idx += 512) {
        int k = idx >> 6;
        int c = idx & 63;
        cdwT[idx] = c_dw[c * 9 + k];
    }
    __syncthreads();

    float acc[8];
#pragma unroll
    for (int i = 0; i < 8; ++i) acc[i] = 0.f;

    for (int k = 0; k < 9; ++k) {
        float wk  = cdwT[k * 64 + lane];          // this lane's channel weight
        float dkx = (float)(k / 3 - 1);
        float dky = (float)(k % 3 - 1);
#pragma unroll
        for (int i = 0; i < 8; ++i) {
            int pix = pix0 + g * 8 + i;           // wave-uniform
            int w = pix & (Wdim - 1);
            int h = (pix >> 7) & (Hdim - 1);
            int b = pix >> 14;

            // wave-uniform offset reads -> scalarized
            float px = (float)(h + 1) + dkx + off[(size_t)k * NPIX + pix];
            float py = (float)(w + 1) + dky + off[(size_t)(k + 9) * NPIX + pix];

            float fx = floorf(px), fy = floorf(py);
            float ltx = fminf(fmaxf(fx, 0.f), 129.f);
            float lty = fminf(fmaxf(fy, 0.f), 129.f);
            float rbx = fminf(fmaxf(fx + 1.f, 0.f), 129.f);
            float rby = fminf(fmaxf(fy + 1.f, 0.f), 129.f);
            float pxc = fminf(fmaxf(px, 0.f), 129.f);
            float pyc = fminf(fmaxf(py, 0.f), 129.f);

            float glt = (1.f + ltx - pxc) * (1.f + lty - pyc);
            float grb = (1.f - rbx + pxc) * (1.f - rby + pyc);
            float glb = (1.f + ltx - pxc) * (1.f - rby + pyc);
            float grt = (1.f - rbx + pxc) * (1.f + lty - pyc);

            int ix0 = (int)ltx, iy0 = (int)lty, ix1 = (int)rbx, iy1 = (int)rby;
            float mx0 = (ix0 >= 1 && ix0 <= Hdim) ? 1.f : 0.f;
            float my0 = (iy0 >= 1 && iy0 <= Wdim) ? 1.f : 0.f;
            float mx1 = (ix1 >= 1 && ix1 <= Hdim) ? 1.f : 0.f;
            float my1 = (iy1 >= 1 && iy1 <= Wdim) ? 1.f : 0.f;
            glt *= mx0 * my0;
            grb *= mx1 * my1;
            glb *= mx0 * my1;
            grt *= mx1 * my0;
            int cx0 = min(max(ix0 - 1, 0), Hdim - 1);
            int cy0 = min(max(iy0 - 1, 0), Wdim - 1);
            int cx1 = min(max(ix1 - 1, 0), Hdim - 1);
            int cy1 = min(max(iy1 - 1, 0), Wdim - 1);

            const float* xb = xt + (size_t)b * HW * Cdim;
            const float* v00 = xb + (size_t)(cx0 * Wdim + cy0) * Cdim;  // lt
            const float* v11 = xb + (size_t)(cx1 * Wdim + cy1) * Cdim;  // rb
            const float* v01 = xb + (size_t)(cx0 * Wdim + cy1) * Cdim;  // lb
            const float* v10 = xb + (size_t)(cx1 * Wdim + cy0) * Cdim;  // rt

            float sv = glt * v00[lane] + grb * v11[lane]
                     + glb * v01[lane] + grt * v10[lane];
            acc[i] += wk * sv;
        }
    }

#pragma unroll
    for (int i = 0; i < 8; ++i) accs[g * 8 + i][lane] = acc[i];
    __syncthreads();

    // Phase B: lane = pixel again; 64->64 pointwise, wave-uniform weights.
    int pix = pix0 + lane;
    int b   = pix >> 14;
    int hw  = pix & (HW - 1);

    float s[8];
#pragma unroll
    for (int i = 0; i < 8; ++i) s[i] = 0.f;

    for (int c0 = 0; c0 < Cdim; c0 += 8) {
        float xc[8];
#pragma unroll
        for (int q = 0; q < 8; ++q) xc[q] = accs[lane][c0 + q];
#pragma unroll
        for (int i = 0; i < 8; ++i) {
#pragma unroll
            for (int q = 0; q < 8; ++q)
                s[i] += c_pw[(g * 8 + i) * Cdim + c0 + q] * xc[q];
        }
    }

    size_t obase = (size_t)b * Cdim * HW + hw;
#pragma unroll
    for (int i = 0; i < 8; ++i)
        out[obase + (size_t)(g * 8 + i) * HW] = s[i];
}

extern "C" void kernel_launch(void* const* d_in, const int* in_sizes, int n_in,
                              void* d_out, int out_size, void* d_ws, size_t ws_size,
                              hipStream_t stream) {
    const float* x    = (const float*)d_in[0];
    const float* p_dw = (const float*)d_in[1];
    const float* p_pw = (const float*)d_in[2];
    const float* c_dw = (const float*)d_in[3];
    const float* c_pw = (const float*)d_in[4];
    float* out = (float*)d_out;
    float* xt  = (float*)d_ws;                    // 16.78 MB  (B,H,W,C)
    float* off = (float*)d_ws + (size_t)NPIX * Cdim;  // 4.72 MB (18, NPIX)

    dim3 blk(512);
    dim3 grd(NBLK);
    transpose_kernel<<<grd, blk, 0, stream>>>(x, xt);
    offset_kernel<<<grd, blk, 0, stream>>>(x, p_dw, p_pw, off);
    deform_kernel<<<grd, blk, 0, stream>>>(xt, c_dw, c_pw, off, out);
}

// Round 6
// 90.834 us; speedup vs baseline: 3.7573x; 1.4040x over previous
//
#include <hip/hip_runtime.h>

#define Hdim 128
#define Wdim 128
#define Cdim 64
#define HW   (Hdim * Wdim)
#define NPIX (4 * HW)     // 65536
#define NBLK (NPIX / 64)  // 1024 blocks, 64 pixels each
#define NXCD 8

// XCD-aware bijective swizzle (nwg % 8 == 0): consecutive logical blocks
// (which share image rows -> x reuse) land on the SAME XCD's L2.
__device__ __forceinline__ int xcd_swizzle(int bid) {
    return (bid % NXCD) * (NBLK / NXCD) + bid / NXCD;
}

// ---------------------------------------------------------------------------
// Kernel 0: NCHW -> NHWC transpose of x (so deform gathers are coalesced:
// one pixel's 64 channels = 256 contiguous bytes).
// ---------------------------------------------------------------------------
__global__ __launch_bounds__(512) void transpose_kernel(
    const float* __restrict__ x,   // (B, C, H, W)
    float* __restrict__ xt)        // (B, H, W, C)
{
    __shared__ float tile[64][65];
    int lane = threadIdx.x & 63;
    int g    = threadIdx.x >> 6;
    int blk  = xcd_swizzle(blockIdx.x);
    int pix0 = blk * 64;
    int b    = pix0 >> 14;
    int hw0  = pix0 & (HW - 1);

#pragma unroll
    for (int i = 0; i < 8; ++i) {
        int c = g * 8 + i;
        tile[c][lane] = x[(size_t)(b * Cdim + c) * HW + hw0 + lane];
    }
    __syncthreads();
#pragma unroll
    for (int i = 0; i < 8; ++i) {
        int p = g * 8 + i;
        xt[(size_t)(pix0 + p) * Cdim + lane] = tile[lane][p];
    }
}

// ---------------------------------------------------------------------------
// Kernel 1: offset = pointwise(p_pw) . depthwise3x3(p_dw) applied to x.
// Output k-major (18, NPIX) so downstream reads are coalesced.
// ---------------------------------------------------------------------------
__global__ __launch_bounds__(512) void offset_kernel(
    const float* __restrict__ x,     // (B, C, H, W)
    const float* __restrict__ p_dw,  // (C, 1, 3, 3)
    const float* __restrict__ p_pw,  // (18, C, 1, 1)
    float* __restrict__ off)         // (18, NPIX)  k-major
{
    __shared__ float part[8][18][64];   // 36.8 KB

    int lane = threadIdx.x & 63;
    int g    = threadIdx.x >> 6;
    int blk  = xcd_swizzle(blockIdx.x);
    int pix0 = blk * 64;
    int pix  = pix0 + lane;
    int w = pix & (Wdim - 1);
    int h = (pix >> 7) & (Hdim - 1);
    int b = pix >> 14;

    float t[8];
#pragma unroll
    for (int i = 0; i < 8; ++i) {
        int c = g * 8 + i;
        const float* xb = x + (size_t)(b * Cdim + c) * HW;
        float s = 0.f;
#pragma unroll
        for (int dh = -1; dh <= 1; ++dh) {
            int hh = h + dh;
            bool okh = (hh >= 0) & (hh < Hdim);
#pragma unroll
            for (int dw = -1; dw <= 1; ++dw) {
                int ww = w + dw;
                bool ok = okh & (ww >= 0) & (ww < Wdim);
                float v = ok ? xb[hh * Wdim + ww] : 0.f;
                s += v * p_dw[c * 9 + (dh + 1) * 3 + (dw + 1)];
            }
        }
        t[i] = s;
    }

#pragma unroll
    for (int j = 0; j < 18; ++j) {
        float s = 0.f;
#pragma unroll
        for (int i = 0; i < 8; ++i)
            s += p_pw[j * Cdim + g * 8 + i] * t[i];
        part[g][j][lane] = s;
    }
    __syncthreads();

#pragma unroll
    for (int it = 0; it < 3; ++it) {
        int idx = threadIdx.x + it * 512;
        if (idx < 18 * 64) {
            int j = idx >> 6;
            int p = idx & 63;
            float s = 0.f;
#pragma unroll
            for (int q = 0; q < 8; ++q) s += part[q][j][p];
            off[(size_t)j * NPIX + pix0 + p] = s;
        }
    }
}

// ---------------------------------------------------------------------------
// Kernel 2: deformable sampling + collapsed depthwise + pointwise.
// Phase 0: geometry (bilinear weights + corner indices) computed ONCE per
//          (pixel,k) pair lane-parallel (576 pairs / 512 thr) -> LDS.
//          (R5 computed it redundantly in all 64 lanes: ~75% of VALU work.)
// Phase A: lane = channel. Wave-uniform float4/int4 geometry broadcast from
//          LDS; per pair just 4 coalesced 256B gathers + 5 FMA.
// Phase B: lane = pixel; 64->64 pointwise, coalesced NCHW writes.
// ---------------------------------------------------------------------------
__global__ __launch_bounds__(512) void deform_kernel(
    const float* __restrict__ xt,    // (B, H, W, C)
    const float* __restrict__ c_dw,  // (C, 1, 3, 3)
    const float* __restrict__ c_pw,  // (C, C, 1, 1)
    const float* __restrict__ off,   // (18, NPIX)
    float* __restrict__ out)         // (B, C, H, W)
{
    __shared__ float  accs[64][65];  // [pixel][channel] padded, 16.6 KB
    __shared__ float4 geoW[9][64];   // bilinear weights, 9.2 KB
    __shared__ int4   geoI[9][64];   // corner pixel indices, 9.2 KB
    __shared__ float  cdwT[9][64];   // c_dw transposed [k][c], 2.3 KB

    int lane = threadIdx.x & 63;
    int g    = threadIdx.x >> 6;
    int blk  = xcd_swizzle(blockIdx.x);
    int pix0 = blk * 64;
    int b    = pix0 >> 14;           // block-uniform (blocks never straddle b)
    const float* xb = xt + (size_t)b * HW * Cdim;

    // stage c_dw transposed
    for (int idx = threadIdx.x; idx < 9 * 64; idx += 512)
        cdwT[idx >> 6][idx & 63] = c_dw[(idx & 63) * 9 + (idx >> 6)];

    // Phase 0: per-(pixel,k) geometry, coalesced k-major offset reads
    for (int idx = threadIdx.x; idx < 9 * 64; idx += 512) {
        int k = idx >> 6;
        int p = idx & 63;
        int pix = pix0 + p;
        int w = pix & (Wdim - 1);
        int h = (pix >> 7) & (Hdim - 1);

        float px = (float)(h + 1) + (float)(k / 3 - 1) + off[(size_t)k * NPIX + pix];
        float py = (float)(w + 1) + (float)(k % 3 - 1) + off[(size_t)(k + 9) * NPIX + pix];

        float fx = floorf(px), fy = floorf(py);
        float ltx = fminf(fmaxf(fx, 0.f), 129.f);
        float lty = fminf(fmaxf(fy, 0.f), 129.f);
        float rbx = fminf(fmaxf(fx + 1.f, 0.f), 129.f);
        float rby = fminf(fmaxf(fy + 1.f, 0.f), 129.f);
        float pxc = fminf(fmaxf(px, 0.f), 129.f);
        float pyc = fminf(fmaxf(py, 0.f), 129.f);

        float glt = (1.f + ltx - pxc) * (1.f + lty - pyc);
        float grb = (1.f - rbx + pxc) * (1.f - rby + pyc);
        float glb = (1.f + ltx - pxc) * (1.f - rby + pyc);
        float grt = (1.f - rbx + pxc) * (1.f + lty - pyc);

        int ix0 = (int)ltx, iy0 = (int)lty, ix1 = (int)rbx, iy1 = (int)rby;
        // padded coord q maps to x coord q-1; nonzero only when 1<=q<=128
        float mx0 = (ix0 >= 1 && ix0 <= Hdim) ? 1.f : 0.f;
        float my0 = (iy0 >= 1 && iy0 <= Wdim) ? 1.f : 0.f;
        float mx1 = (ix1 >= 1 && ix1 <= Hdim) ? 1.f : 0.f;
        float my1 = (iy1 >= 1 && iy1 <= Wdim) ? 1.f : 0.f;
        glt *= mx0 * my0;
        grb *= mx1 * my1;
        glb *= mx0 * my1;
        grt *= mx1 * my0;
        int cx0 = min(max(ix0 - 1, 0), Hdim - 1);
        int cy0 = min(max(iy0 - 1, 0), Wdim - 1);
        int cx1 = min(max(ix1 - 1, 0), Hdim - 1);
        int cy1 = min(max(iy1 - 1, 0), Wdim - 1);

        geoW[k][p] = make_float4(glt, grb, glb, grt);
        geoI[k][p] = make_int4(cx0 * Wdim + cy0,   // lt
                               cx1 * Wdim + cy1,   // rb
                               cx0 * Wdim + cy1,   // lb
                               cx1 * Wdim + cy0);  // rt
    }
    __syncthreads();

    // Phase A: lane = channel; wave-uniform geometry broadcast, coalesced gathers
    float acc[8];
#pragma unroll
    for (int i = 0; i < 8; ++i) acc[i] = 0.f;

    for (int k = 0; k < 9; ++k) {
        float wk = cdwT[k][lane];
#pragma unroll
        for (int i = 0; i < 8; ++i) {
            int p = g * 8 + i;                    // wave-uniform
            float4 wv = geoW[k][p];
            int4   iv = geoI[k][p];
            float sv = wv.x * xb[(size_t)iv.x * Cdim + lane]
                     + wv.y * xb[(size_t)iv.y * Cdim + lane]
                     + wv.z * xb[(size_t)iv.z * Cdim + lane]
                     + wv.w * xb[(size_t)iv.w * Cdim + lane];
            acc[i] += wk * sv;
        }
    }

#pragma unroll
    for (int i = 0; i < 8; ++i) accs[g * 8 + i][lane] = acc[i];
    __syncthreads();

    // Phase B: lane = pixel; 64->64 pointwise, wave-uniform weights.
    int pix = pix0 + lane;
    int hw  = pix & (HW - 1);

    float s[8];
#pragma unroll
    for (int i = 0; i < 8; ++i) s[i] = 0.f;

    for (int c0 = 0; c0 < Cdim; c0 += 8) {
        float xc[8];
#pragma unroll
        for (int q = 0; q < 8; ++q) xc[q] = accs[lane][c0 + q];
#pragma unroll
        for (int i = 0; i < 8; ++i) {
#pragma unroll
            for (int q = 0; q < 8; ++q)
                s[i] += c_pw[(g * 8 + i) * Cdim + c0 + q] * xc[q];
        }
    }

    size_t obase = (size_t)b * Cdim * HW + hw;
#pragma unroll
    for (int i = 0; i < 8; ++i)
        out[obase + (size_t)(g * 8 + i) * HW] = s[i];
}

extern "C" void kernel_launch(void* const* d_in, const int* in_sizes, int n_in,
                              void* d_out, int out_size, void* d_ws, size_t ws_size,
                              hipStream_t stream) {
    const float* x    = (const float*)d_in[0];
    const float* p_dw = (const float*)d_in[1];
    const float* p_pw = (const float*)d_in[2];
    const float* c_dw = (const float*)d_in[3];
    const float* c_pw = (const float*)d_in[4];
    float* out = (float*)d_out;
    float* xt  = (float*)d_ws;                        // 16.78 MB  (B,H,W,C)
    float* off = (float*)d_ws + (size_t)NPIX * Cdim;  // 4.72 MB (18, NPIX)

    dim3 blk(512);
    dim3 grd(NBLK);
    transpose_kernel<<<grd, blk, 0, stream>>>(x, xt);
    offset_kernel<<<grd, blk, 0, stream>>>(x, p_dw, p_pw, off);
    deform_kernel<<<grd, blk, 0, stream>>>(xt, c_dw, c_pw, off, out);
}

// Round 7
// 72.719 us; speedup vs baseline: 4.6932x; 1.2491x over previous
//
#include <hip/hip_runtime.h>

#define Hdim 128
#define Wdim 128
#define Cdim 64
#define HW   (Hdim * Wdim)
#define NPIX (4 * HW)     // 65536
#define NBLK (NPIX / 64)  // 1024 blocks, 64 pixels each
#define NXCD 8

// XCD-aware bijective swizzle (nwg % 8 == 0): consecutive logical blocks
// (which share image rows -> x reuse) land on the SAME XCD's L2.
__device__ __forceinline__ int xcd_swizzle(int bid) {
    return (bid % NXCD) * (NBLK / NXCD) + bid / NXCD;
}

// ---------------------------------------------------------------------------
// Kernel 0: NCHW -> NHWC transpose of x (so deform gathers are coalesced:
// one pixel's 64 channels = 256 contiguous bytes).
// ---------------------------------------------------------------------------
__global__ __launch_bounds__(512) void transpose_kernel(
    const float* __restrict__ x,   // (B, C, H, W)
    float* __restrict__ xt)        // (B, H, W, C)
{
    __shared__ float tile[64][65];
    int lane = threadIdx.x & 63;
    int g    = threadIdx.x >> 6;
    int blk  = xcd_swizzle(blockIdx.x);
    int pix0 = blk * 64;
    int b    = pix0 >> 14;
    int hw0  = pix0 & (HW - 1);

#pragma unroll
    for (int i = 0; i < 8; ++i) {
        int c = g * 8 + i;
        tile[c][lane] = x[(size_t)(b * Cdim + c) * HW + hw0 + lane];
    }
    __syncthreads();
#pragma unroll
    for (int i = 0; i < 8; ++i) {
        int p = g * 8 + i;
        xt[(size_t)(pix0 + p) * Cdim + lane] = tile[lane][p];
    }
}

// ---------------------------------------------------------------------------
// Kernel 1: offset conv (dw 3x3 + pw 64->18) AND sampling geometry.
// After the LDS reduce of the 18 offset values per pixel, a geometry pass
// computes bilinear weights + corner indices per (pixel,k) and writes them
// to global scratch [blk][k][p] so the deform kernel can read them
// wave-uniformly (s_load) with ZERO LDS traffic. The off array is never
// materialized in global memory.
// ---------------------------------------------------------------------------
__global__ __launch_bounds__(512) void offset_kernel(
    const float* __restrict__ x,     // (B, C, H, W)
    const float* __restrict__ p_dw,  // (C, 1, 3, 3)
    const float* __restrict__ p_pw,  // (18, C, 1, 1)
    float4* __restrict__ geoW,       // (NBLK, 9, 64) bilinear weights
    int4* __restrict__ geoI)         // (NBLK, 9, 64) corner indices
{
    __shared__ float part[8][18][64];   // 36.8 KB; part[0] reused as sum

    int lane = threadIdx.x & 63;
    int g    = threadIdx.x >> 6;
    int blk  = xcd_swizzle(blockIdx.x);
    int pix0 = blk * 64;
    int pix  = pix0 + lane;
    int w = pix & (Wdim - 1);
    int h = (pix >> 7) & (Hdim - 1);
    int b = pix >> 14;

    float t[8];
#pragma unroll
    for (int i = 0; i < 8; ++i) {
        int c = g * 8 + i;
        const float* xb = x + (size_t)(b * Cdim + c) * HW;
        float s = 0.f;
#pragma unroll
        for (int dh = -1; dh <= 1; ++dh) {
            int hh = h + dh;
            bool okh = (hh >= 0) & (hh < Hdim);
#pragma unroll
            for (int dw = -1; dw <= 1; ++dw) {
                int ww = w + dw;
                bool ok = okh & (ww >= 0) & (ww < Wdim);
                float v = ok ? xb[hh * Wdim + ww] : 0.f;
                s += v * p_dw[c * 9 + (dh + 1) * 3 + (dw + 1)];
            }
        }
        t[i] = s;
    }

#pragma unroll
    for (int j = 0; j < 18; ++j) {
        float s = 0.f;
#pragma unroll
        for (int i = 0; i < 8; ++i)
            s += p_pw[j * Cdim + g * 8 + i] * t[i];
        part[g][j][lane] = s;
    }
    __syncthreads();

    // reduce 8 partials into part[0] (each (j,p) read+written by one thread)
#pragma unroll
    for (int it = 0; it < 3; ++it) {
        int idx = threadIdx.x + it * 512;
        if (idx < 18 * 64) {
            int j = idx >> 6;
            int p = idx & 63;
            float s = part[0][j][p];
#pragma unroll
            for (int q = 1; q < 8; ++q) s += part[q][j][p];
            part[0][j][p] = s;
        }
    }
    __syncthreads();

    // geometry pass: 576 (k,p) pairs
#pragma unroll
    for (int it = 0; it < 2; ++it) {
        int idx = threadIdx.x + it * 512;
        if (idx < 9 * 64) {
            int k = idx >> 6;
            int p = idx & 63;
            int ppix = pix0 + p;
            int pw2 = ppix & (Wdim - 1);
            int ph2 = (ppix >> 7) & (Hdim - 1);

            float px = (float)(ph2 + 1) + (float)(k / 3 - 1) + part[0][k][p];
            float py = (float)(pw2 + 1) + (float)(k % 3 - 1) + part[0][k + 9][p];

            float fx = floorf(px), fy = floorf(py);
            float ltx = fminf(fmaxf(fx, 0.f), 129.f);
            float lty = fminf(fmaxf(fy, 0.f), 129.f);
            float rbx = fminf(fmaxf(fx + 1.f, 0.f), 129.f);
            float rby = fminf(fmaxf(fy + 1.f, 0.f), 129.f);
            float pxc = fminf(fmaxf(px, 0.f), 129.f);
            float pyc = fminf(fmaxf(py, 0.f), 129.f);

            float glt = (1.f + ltx - pxc) * (1.f + lty - pyc);
            float grb = (1.f - rbx + pxc) * (1.f - rby + pyc);
            float glb = (1.f + ltx - pxc) * (1.f - rby + pyc);
            float grt = (1.f - rbx + pxc) * (1.f + lty - pyc);

            int ix0 = (int)ltx, iy0 = (int)lty, ix1 = (int)rbx, iy1 = (int)rby;
            // padded coord q maps to x coord q-1; nonzero only when 1<=q<=128
            float mx0 = (ix0 >= 1 && ix0 <= Hdim) ? 1.f : 0.f;
            float my0 = (iy0 >= 1 && iy0 <= Wdim) ? 1.f : 0.f;
            float mx1 = (ix1 >= 1 && ix1 <= Hdim) ? 1.f : 0.f;
            float my1 = (iy1 >= 1 && iy1 <= Wdim) ? 1.f : 0.f;
            glt *= mx0 * my0;
            grb *= mx1 * my1;
            glb *= mx0 * my1;
            grt *= mx1 * my0;
            int cx0 = min(max(ix0 - 1, 0), Hdim - 1);
            int cy0 = min(max(iy0 - 1, 0), Wdim - 1);
            int cx1 = min(max(ix1 - 1, 0), Hdim - 1);
            int cy1 = min(max(iy1 - 1, 0), Wdim - 1);

            size_t gidx = ((size_t)blk * 9 + k) * 64 + p;
            geoW[gidx] = make_float4(glt, grb, glb, grt);
            geoI[gidx] = make_int4(cx0 * Wdim + cy0,   // lt
                                   cx1 * Wdim + cy1,   // rb
                                   cx0 * Wdim + cy1,   // lb
                                   cx1 * Wdim + cy0);  // rt
        }
    }
}

// ---------------------------------------------------------------------------
// Kernel 2: deformable sampling + collapsed depthwise + pointwise.
// Phase A: lane = channel. Geometry read wave-uniformly from global scratch
//          (readfirstlane'd wave id -> scalarized loads), no LDS broadcast
//          (R6 spent ~23us/CU of LDS-pipe time on 144 ds_read_b128/wave).
// Phase B: lane = pixel; 64->64 pointwise, coalesced NCHW writes.
// ---------------------------------------------------------------------------
__global__ __launch_bounds__(512) void deform_kernel(
    const float* __restrict__ xt,    // (B, H, W, C)
    const float* __restrict__ c_dw,  // (C, 1, 3, 3)
    const float* __restrict__ c_pw,  // (C, C, 1, 1)
    const float4* __restrict__ geoW, // (NBLK, 9, 64)
    const int4* __restrict__ geoI,   // (NBLK, 9, 64)
    float* __restrict__ out)         // (B, C, H, W)
{
    __shared__ float accs[64][65];   // [pixel][channel] padded, 16.6 KB
    __shared__ float cdwT[9][64];    // c_dw transposed [k][c], 2.3 KB

    int lane = threadIdx.x & 63;
    int gu   = __builtin_amdgcn_readfirstlane(threadIdx.x >> 6);  // uniform wave id
    int blk  = xcd_swizzle(blockIdx.x);
    int pix0 = blk * 64;
    int b    = pix0 >> 14;           // block-uniform (blocks never straddle b)
    const float* xb = xt + (size_t)b * HW * Cdim;

    for (int idx = threadIdx.x; idx < 9 * 64; idx += 512)
        cdwT[idx >> 6][idx & 63] = c_dw[(idx & 63) * 9 + (idx >> 6)];
    __syncthreads();

    // Phase A: lane = channel; wave-uniform geometry, coalesced 256B gathers
    float acc[8];
#pragma unroll
    for (int i = 0; i < 8; ++i) acc[i] = 0.f;

    for (int k = 0; k < 9; ++k) {
        float wk = cdwT[k][lane];
        const float4* gW = geoW + ((size_t)blk * 9 + k) * 64 + gu * 8;
        const int4*   gI = geoI + ((size_t)blk * 9 + k) * 64 + gu * 8;
#pragma unroll
        for (int i = 0; i < 8; ++i) {
            float4 wv = gW[i];       // wave-uniform -> scalarized
            int4   iv = gI[i];
            float sv = wv.x * xb[iv.x * Cdim + lane]
                     + wv.y * xb[iv.y * Cdim + lane]
                     + wv.z * xb[iv.z * Cdim + lane]
                     + wv.w * xb[iv.w * Cdim + lane];
            acc[i] += wk * sv;
        }
    }

#pragma unroll
    for (int i = 0; i < 8; ++i) accs[gu * 8 + i][lane] = acc[i];
    __syncthreads();

    // Phase B: lane = pixel; 64->64 pointwise, wave-uniform weights.
    int pix = pix0 + lane;
    int hw  = pix & (HW - 1);

    float s[8];
#pragma unroll
    for (int i = 0; i < 8; ++i) s[i] = 0.f;

    for (int c0 = 0; c0 < Cdim; c0 += 8) {
        float xc[8];
#pragma unroll
        for (int q = 0; q < 8; ++q) xc[q] = accs[lane][c0 + q];
#pragma unroll
        for (int i = 0; i < 8; ++i) {
#pragma unroll
            for (int q = 0; q < 8; ++q)
                s[i] += c_pw[(gu * 8 + i) * Cdim + c0 + q] * xc[q];
        }
    }

    size_t obase = (size_t)b * Cdim * HW + hw;
#pragma unroll
    for (int i = 0; i < 8; ++i)
        out[obase + (size_t)(gu * 8 + i) * HW] = s[i];
}

extern "C" void kernel_launch(void* const* d_in, const int* in_sizes, int n_in,
                              void* d_out, int out_size, void* d_ws, size_t ws_size,
                              hipStream_t stream) {
    const float* x    = (const float*)d_in[0];
    const float* p_dw = (const float*)d_in[1];
    const float* p_pw = (const float*)d_in[2];
    const float* c_dw = (const float*)d_in[3];
    const float* c_pw = (const float*)d_in[4];
    float* out = (float*)d_out;

    float*  xt   = (float*)d_ws;                              // 16.78 MB
    float4* geoW = (float4*)((char*)d_ws + (size_t)NPIX * Cdim * 4);          // 9.44 MB
    int4*   geoI = (int4*)((char*)geoW + (size_t)NBLK * 9 * 64 * sizeof(float4)); // 9.44 MB

    dim3 blk(512);
    dim3 grd(NBLK);
    transpose_kernel<<<grd, blk, 0, stream>>>(x, xt);
    offset_kernel<<<grd, blk, 0, stream>>>(x, p_dw, p_pw, geoW, geoI);
    deform_kernel<<<grd, blk, 0, stream>>>(xt, c_dw, c_pw, geoW, geoI, out);
}

// Round 8
// 66.634 us; speedup vs baseline: 5.1218x; 1.0913x over previous
//
#include <hip/hip_runtime.h>

#define Hdim 128
#define Wdim 128
#define Cdim 64
#define HW   (Hdim * Wdim)
#define NPIX (4 * HW)     // 65536
#define NBLK (NPIX / 64)  // 1024 blocks, 64 pixels each
#define NXCD 8
#define Hp 130            // padded dims
#define HWp (Hp * Hp)     // 16900

// XCD-aware bijective swizzle (nwg % 8 == 0): consecutive logical blocks
// (which share image rows -> x reuse) land on the SAME XCD's L2.
__device__ __forceinline__ int xcd_swizzle(int bid) {
    return (bid % NXCD) * (NBLK / NXCD) + bid / NXCD;
}

// ---------------------------------------------------------------------------
// Kernel A: fused {NCHW->padded-NHWC transpose} + {offset conv dw3x3 + pw
// 64->18} + {sampling geometry}.
//  - x is read ONCE (stencil); the center tap doubles as the transpose source.
//  - xt_pad is (B,130,130,C) with a zero ring = the reference's jnp.pad image,
//    so geometry needs NO validity masks (coords clip to [0,129] verbatim).
//  - geometry written to global scratch [blk][k][p] for wave-uniform s_load
//    consumption in the deform kernel.
// ---------------------------------------------------------------------------
__global__ __launch_bounds__(512) void offset_geo_kernel(
    const float* __restrict__ x,     // (B, C, H, W)
    const float* __restrict__ p_dw,  // (C, 1, 3, 3)
    const float* __restrict__ p_pw,  // (18, C, 1, 1)
    float* __restrict__ xt,          // (B, 130, 130, C) padded NHWC
    float4* __restrict__ geoW,       // (NBLK, 9, 64) bilinear weights
    int4* __restrict__ geoI)         // (NBLK, 9, 64) padded-grid corner idx
{
    __shared__ float part[8][18][64];   // 36.8 KB; part[0] reused as sum

    int lane = threadIdx.x & 63;
    int g    = threadIdx.x >> 6;
    int blk  = xcd_swizzle(blockIdx.x);
    int pix0 = blk * 64;
    int pix  = pix0 + lane;
    int w = pix & (Wdim - 1);
    int h = (pix >> 7) & (Hdim - 1);
    int b = pix >> 14;

    // --- zero the pad ring of xt (2064 ring positions x 16 float4) -------
    {
        int gid = blockIdx.x * 512 + threadIdx.x;   // raw id: blocks 0..64
        if (gid < 2064 * 16) {
            int rp  = gid >> 4, sub = gid & 15;
            int img = rp / 516, pos = rp - img * 516;
            int i, j;
            if (pos < 130)      { i = 0;   j = pos; }
            else if (pos < 260) { i = 129; j = pos - 130; }
            else { int p2 = pos - 260; i = 1 + (p2 >> 1); j = (p2 & 1) ? 129 : 0; }
            float4* dst = (float4*)(xt + ((size_t)img * HWp + i * Hp + j) * Cdim);
            dst[sub] = make_float4(0.f, 0.f, 0.f, 0.f);
        }
    }

    // --- depthwise 3x3: masks/offsets hoisted out of the channel loop ----
    int   off9[9];
    float msk9[9];
#pragma unroll
    for (int dh = -1; dh <= 1; ++dh) {
#pragma unroll
        for (int dw = -1; dw <= 1; ++dw) {
            int tap = (dh + 1) * 3 + (dw + 1);
            int hh = h + dh, ww = w + dw;
            bool ok = (hh >= 0) & (hh < Hdim) & (ww >= 0) & (ww < Wdim);
            off9[tap] = ok ? hh * Wdim + ww : 0;
            msk9[tap] = ok ? 1.f : 0.f;
        }
    }

    float t[8], ctr[8];
#pragma unroll
    for (int i = 0; i < 8; ++i) {
        int c = g * 8 + i;              // wave-uniform
        const float* xb = x + (size_t)(b * Cdim + c) * HW;
        float s = 0.f;
#pragma unroll
        for (int tap = 0; tap < 9; ++tap) {
            float v = xb[off9[tap]] * msk9[tap];
            s += v * p_dw[c * 9 + tap];
        }
        t[i]   = s;
        ctr[i] = xb[h * Wdim + w];      // transpose source (center tap)
    }

    // --- transpose write: 8 contiguous floats per thread (32B chunks) ----
    {
        size_t ppos = ((size_t)b * HWp + (h + 1) * Hp + (w + 1)) * Cdim + g * 8;
        float4* cd = (float4*)(xt + ppos);
        cd[0] = make_float4(ctr[0], ctr[1], ctr[2], ctr[3]);
        cd[1] = make_float4(ctr[4], ctr[5], ctr[6], ctr[7]);
    }

    // --- pointwise 64->18 partials -> LDS ---------------------------------
#pragma unroll
    for (int j = 0; j < 18; ++j) {
        float s = 0.f;
#pragma unroll
        for (int i = 0; i < 8; ++i)
            s += p_pw[j * Cdim + g * 8 + i] * t[i];
        part[g][j][lane] = s;
    }
    __syncthreads();

    // reduce 8 partials into part[0]
#pragma unroll
    for (int it = 0; it < 3; ++it) {
        int idx = threadIdx.x + it * 512;
        if (idx < 18 * 64) {
            int j = idx >> 6;
            int p = idx & 63;
            float s = part[0][j][p];
#pragma unroll
            for (int q = 1; q < 8; ++q) s += part[q][j][p];
            part[0][j][p] = s;
        }
    }
    __syncthreads();

    // --- geometry pass: reference formulas verbatim on the padded grid ---
#pragma unroll
    for (int it = 0; it < 2; ++it) {
        int idx = threadIdx.x + it * 512;
        if (idx < 9 * 64) {
            int k = idx >> 6;
            int p = idx & 63;
            int ppix = pix0 + p;
            int pw2 = ppix & (Wdim - 1);
            int ph2 = (ppix >> 7) & (Hdim - 1);

            float px = (float)(ph2 + 1) + (float)(k / 3 - 1) + part[0][k][p];
            float py = (float)(pw2 + 1) + (float)(k % 3 - 1) + part[0][k + 9][p];

            float fx = floorf(px), fy = floorf(py);
            float ltx = fminf(fmaxf(fx, 0.f), 129.f);
            float lty = fminf(fmaxf(fy, 0.f), 129.f);
            float rbx = fminf(fmaxf(fx + 1.f, 0.f), 129.f);
            float rby = fminf(fmaxf(fy + 1.f, 0.f), 129.f);
            float pxc = fminf(fmaxf(px, 0.f), 129.f);
            float pyc = fminf(fmaxf(py, 0.f), 129.f);

            float glt = (1.f + ltx - pxc) * (1.f + lty - pyc);
            float grb = (1.f - rbx + pxc) * (1.f - rby + pyc);
            float glb = (1.f + ltx - pxc) * (1.f - rby + pyc);
            float grt = (1.f - rbx + pxc) * (1.f + lty - pyc);

            int ix0 = (int)ltx, iy0 = (int)lty, ix1 = (int)rbx, iy1 = (int)rby;

            size_t gidx = ((size_t)blk * 9 + k) * 64 + p;
            geoW[gidx] = make_float4(glt, grb, glb, grt);
            geoI[gidx] = make_int4(ix0 * Hp + iy0,   // lt
                                   ix1 * Hp + iy1,   // rb
                                   ix0 * Hp + iy1,   // lb
                                   ix1 * Hp + iy0);  // rt
        }
    }
}

// ---------------------------------------------------------------------------
// Kernel B: deformable sampling + collapsed depthwise + pointwise.
// Phase A: lane = channel; wave-uniform geometry via scalar loads from
//          global scratch; 4 coalesced 256B gathers + 5 FMA per (pixel,k).
// Phase B: lane = pixel; 64->64 pointwise, coalesced NCHW writes.
// ---------------------------------------------------------------------------
__global__ __launch_bounds__(512) void deform_kernel(
    const float* __restrict__ xt,    // (B, 130, 130, C) padded NHWC
    const float* __restrict__ c_dw,  // (C, 1, 3, 3)
    const float* __restrict__ c_pw,  // (C, C, 1, 1)
    const float4* __restrict__ geoW, // (NBLK, 9, 64)
    const int4* __restrict__ geoI,   // (NBLK, 9, 64)
    float* __restrict__ out)         // (B, C, H, W)
{
    __shared__ float accs[64][65];   // [pixel][channel] padded, 16.6 KB
    __shared__ float cdwT[9][64];    // c_dw transposed [k][c], 2.3 KB

    int lane = threadIdx.x & 63;
    int gu   = __builtin_amdgcn_readfirstlane(threadIdx.x >> 6);  // uniform wave id
    int blk  = xcd_swizzle(blockIdx.x);
    int pix0 = blk * 64;
    int b    = pix0 >> 14;           // block-uniform (blocks never straddle b)
    const float* xb = xt + (size_t)b * HWp * Cdim;

    for (int idx = threadIdx.x; idx < 9 * 64; idx += 512)
        cdwT[idx >> 6][idx & 63] = c_dw[(idx & 63) * 9 + (idx >> 6)];
    __syncthreads();

    // Phase A: lane = channel; wave-uniform geometry, coalesced 256B gathers
    float acc[8];
#pragma unroll
    for (int i = 0; i < 8; ++i) acc[i] = 0.f;

    for (int k = 0; k < 9; ++k) {
        float wk = cdwT[k][lane];
        const float4* gW = geoW + ((size_t)blk * 9 + k) * 64 + gu * 8;
        const int4*   gI = geoI + ((size_t)blk * 9 + k) * 64 + gu * 8;
#pragma unroll
        for (int i = 0; i < 8; ++i) {
            float4 wv = gW[i];       // wave-uniform -> scalarized
            int4   iv = gI[i];
            float sv = wv.x * xb[iv.x * Cdim + lane]
                     + wv.y * xb[iv.y * Cdim + lane]
                     + wv.z * xb[iv.z * Cdim + lane]
                     + wv.w * xb[iv.w * Cdim + lane];
            acc[i] += wk * sv;
        }
    }

#pragma unroll
    for (int i = 0; i < 8; ++i) accs[gu * 8 + i][lane] = acc[i];
    __syncthreads();

    // Phase B: lane = pixel; 64->64 pointwise, wave-uniform weights.
    int pix = pix0 + lane;
    int hw  = pix & (HW - 1);

    float s[8];
#pragma unroll
    for (int i = 0; i < 8; ++i) s[i] = 0.f;

    for (int c0 = 0; c0 < Cdim; c0 += 8) {
        float xc[8];
#pragma unroll
        for (int q = 0; q < 8; ++q) xc[q] = accs[lane][c0 + q];
#pragma unroll
        for (int i = 0; i < 8; ++i) {
#pragma unroll
            for (int q = 0; q < 8; ++q)
                s[i] += c_pw[(gu * 8 + i) * Cdim + c0 + q] * xc[q];
        }
    }

    size_t obase = (size_t)b * Cdim * HW + hw;
#pragma unroll
    for (int i = 0; i < 8; ++i)
        out[obase + (size_t)(gu * 8 + i) * HW] = s[i];
}

extern "C" void kernel_launch(void* const* d_in, const int* in_sizes, int n_in,
                              void* d_out, int out_size, void* d_ws, size_t ws_size,
                              hipStream_t stream) {
    const float* x    = (const float*)d_in[0];
    const float* p_dw = (const float*)d_in[1];
    const float* p_pw = (const float*)d_in[2];
    const float* c_dw = (const float*)d_in[3];
    const float* c_pw = (const float*)d_in[4];
    float* out = (float*)d_out;

    float*  xt   = (float*)d_ws;                                   // 17.3 MB padded NHWC
    float4* geoW = (float4*)((char*)d_ws + (size_t)4 * HWp * Cdim * 4);
    int4*   geoI = (int4*)((char*)geoW + (size_t)NBLK * 9 * 64 * sizeof(float4));

    dim3 blk(512);
    dim3 grd(NBLK);
    offset_geo_kernel<<<grd, blk, 0, stream>>>(x, p_dw, p_pw, xt, geoW, geoI);
    deform_kernel<<<grd, blk, 0, stream>>>(xt, c_dw, c_pw, geoW, geoI, out);
}